// Round 1
// baseline (288.842 us; speedup 1.0000x reference)
//
#include <hip/hip_runtime.h>
#include <math.h>

#define S_LEN 2048
#define D_KV  64
#define BQ    64      // q rows per block (4 waves x 16, x2 split-K groups)
#define BK    64
#define KHALF 1024

typedef __attribute__((ext_vector_type(8))) short bh8;   // 8 bf16 (MFMA A/B frag)
typedef __attribute__((ext_vector_type(4))) float fx4;   // MFMA C/D frag / float4
typedef __attribute__((ext_vector_type(4))) unsigned int u32x4;
typedef __attribute__((ext_vector_type(2))) unsigned int u32x2;

__device__ __forceinline__ unsigned cvt2(float a, float b) {
    unsigned r;
    asm("v_cvt_pk_bf16_f32 %0, %1, %2" : "=v"(r) : "v"(a), "v"(b));
    return r;
}

// XOR-swizzled byte offsets (same function on write and read — both-sides rule)
__device__ __forceinline__ int kswz(int row, int dkb) {
    return ((row << 7) + dkb) ^ ((row & 7) << 4);
}
__device__ __forceinline__ int vswz(int d, int colb) {
    return ((d << 7) + colb) ^ (((d >> 2) & 7) << 4);
}

__global__ __launch_bounds__(512, 6)
void attn_fwd(const float* __restrict__ Qg, const float* __restrict__ Kg,
              const float* __restrict__ Vg, const float* __restrict__ Mg,
              float* __restrict__ Og)
{
    // [0,16384): K tiles (2 groups x [64][64] bf16, swizzled)
    // [16384,32768): V^T tiles (2 groups, slot-permuted cols, swizzled)
    // epilogue: reused as float scratch for split-K combine (20480 B)
    __shared__ __align__(16) char smem[32768];

    const int tid  = threadIdx.x;
    const int wave = tid >> 6;
    const int lane = tid & 63;
    const int g    = lane >> 4;   // quad 0..3
    const int c    = lane & 15;   // q row within wave tile
    const int kg   = wave >> 2;   // split-K group (0: k<1024, 1: k>=1024)
    const int tidg = tid & 255;   // thread id within group

    const int qt = blockIdx.x;    // 0..31
    const int bh = blockIdx.y;    // 0..31
    const int b  = bh >> 4;

    const int qbase = qt * BQ + (wave & 3) * 16;

    short* kb = (short*)(smem) + kg * 4096;
    short* vb = (short*)(smem + 16384) + kg * 4096;

    const float* Kp = Kg + (size_t)bh * S_LEN * D_KV;
    const float* Vp = Vg + (size_t)bh * S_LEN * D_KV;
    const float* Qp = Qg + ((size_t)bh * S_LEN + qbase) * D_KV;
    const float* mrow = Mg + (size_t)b * S_LEN * S_LEN
                      + (size_t)(qbase + c) * S_LEN + g * 4;

    // ---- Q as B-frag (col = q = c), scale 1/8 folded in ----
    bh8 qf[2];
#pragma unroll
    for (int kc = 0; kc < 2; ++kc) {
        const float* src = Qp + c * D_KV + kc * 32 + g * 8;
        fx4 a0 = *(const fx4*)(src);
        fx4 a1 = *(const fx4*)(src + 4);
        u32x4 q4 = { cvt2(a0[0] * 0.125f, a0[1] * 0.125f),
                     cvt2(a0[2] * 0.125f, a0[3] * 0.125f),
                     cvt2(a1[0] * 0.125f, a1[1] * 0.125f),
                     cvt2(a1[2] * 0.125f, a1[3] * 0.125f) };
        qf[kc] = __builtin_bit_cast(bh8, q4);
    }

    fx4 o[4];                 // O[q=c][d = u*16 + g*4 + r]
#pragma unroll
    for (int u = 0; u < 4; ++u) { fx4 z = {0.f, 0.f, 0.f, 0.f}; o[u] = z; }
    float l = 0.f;            // partial row sum (this lane's 16 keys/tile)

    // V staging: 4x4 in-register transpose block
    const int vk0 = (tidg >> 4) << 2;
    const int vd0 = (tidg & 15) << 2;
    // slot-permuted column base: col(s) = ((s&15)>>2)*16 + (s>>4)*4 + (s&3)
    const int vcolb = (((vk0 & 15) >> 2) << 5) + ((vk0 >> 4) << 3);  // bytes

    for (int it = 0; it < 16; ++it) {
        const int kt = kg * KHALF + it * BK;

        // ---- stage K: rows natural order, swizzled ----
#pragma unroll
        for (int i = 0; i < 4; ++i) {
            const int idx = tidg + 256 * i;
            const int kr  = idx >> 4;
            const int de  = (idx & 15) << 2;
            fx4 t4 = *(const fx4*)(Kp + (size_t)(kt + kr) * D_KV + de);
            u32x2 w = { cvt2(t4[0], t4[1]), cvt2(t4[2], t4[3]) };
            *(u32x2*)((char*)kb + kswz(kr, de << 1)) = w;
        }
        // ---- stage V^T: [d][permuted k-slot], vectorized via 4x4 transpose ----
        {
            const float* vsrc = Vp + (size_t)(kt + vk0) * D_KV + vd0;
            fx4 r0 = *(const fx4*)(vsrc);
            fx4 r1 = *(const fx4*)(vsrc + D_KV);
            fx4 r2 = *(const fx4*)(vsrc + 2 * D_KV);
            fx4 r3 = *(const fx4*)(vsrc + 3 * D_KV);
#pragma unroll
            for (int i = 0; i < 4; ++i) {
                u32x2 w = { cvt2(r0[i], r1[i]), cvt2(r2[i], r3[i]) };
                *(u32x2*)((char*)vb + vswz(vd0 + i, vcolb)) = w;
            }
        }
        __syncthreads();

        // ---- mask loads: contiguous in k now -> float4 (issue early) ----
        fx4 mv[4];
#pragma unroll
        for (int t = 0; t < 4; ++t)
            mv[t] = *(const fx4*)(mrow + kt + t * 16);

        // ---- QK^T swapped: st[t] lane(c,g) reg r = S[q=c][key = t*16+g*4+r] ----
        fx4 st[4];
#pragma unroll
        for (int t = 0; t < 4; ++t) { fx4 z = {0.f, 0.f, 0.f, 0.f}; st[t] = z; }
#pragma unroll
        for (int kc = 0; kc < 2; ++kc) {
#pragma unroll
            for (int t = 0; t < 4; ++t) {
                bh8 kf = *(const bh8*)((char*)kb + kswz(t * 16 + c, (kc << 6) + (g << 4)));
                st[t] = __builtin_amdgcn_mfma_f32_16x16x32_bf16(kf, qf[kc], st[t], 0, 0, 0);
            }
        }

        // ---- mask * keep-positive * exp (fixed max 0), pack to bf16 in-register ----
        unsigned pk[8];
#pragma unroll
        for (int t = 0; t < 4; ++t) {
            float tm0 = st[t][0] * mv[t][0];
            float tm1 = st[t][1] * mv[t][1];
            float tm2 = st[t][2] * mv[t][2];
            float tm3 = st[t][3] * mv[t][3];
            float p0 = tm0 > 0.f ? __expf(tm0) : 0.f;
            float p1 = tm1 > 0.f ? __expf(tm1) : 0.f;
            float p2 = tm2 > 0.f ? __expf(tm2) : 0.f;
            float p3 = tm3 > 0.f ? __expf(tm3) : 0.f;
            l += (p0 + p1) + (p2 + p3);
            pk[t * 2 + 0] = cvt2(p0, p1);
            pk[t * 2 + 1] = cvt2(p2, p3);
        }

        // ---- PV: o[u] += V^T_frag(A) x P(B); P fed straight from registers ----
        // slot s = g*8+j of mfma #(tp) <-> key (2tp + j/4)*16 + g*4 + (j&3),
        // matched on the V side by the permuted column layout.
#pragma unroll
        for (int tp = 0; tp < 2; ++tp) {
            u32x4 pq = { pk[tp * 4 + 0], pk[tp * 4 + 1],
                         pk[tp * 4 + 2], pk[tp * 4 + 3] };
            bh8 pp = __builtin_bit_cast(bh8, pq);
#pragma unroll
            for (int u = 0; u < 4; ++u) {
                bh8 vv = *(const bh8*)((char*)vb + vswz(u * 16 + c, (g << 5) + (tp << 4)));
                o[u] = __builtin_amdgcn_mfma_f32_16x16x32_bf16(vv, pp, o[u], 0, 0, 0);
            }
        }
        __syncthreads();   // protect k/v LDS before next staging
    }

    // ---- reduce l across the 4 g-groups sharing row q=c ----
    l += __shfl_xor(l, 16);
    l += __shfl_xor(l, 32);

    // ---- split-K combine: fixed-max softmax => partials add linearly ----
    __syncthreads();
    float* scr = (float*)smem;
    if (wave >= 4) {
        float* dst = scr + ((wave - 4) * 64 + lane) * 20;
#pragma unroll
        for (int u = 0; u < 4; ++u) *(fx4*)(dst + u * 4) = o[u];
        dst[16] = l;
    }
    __syncthreads();
    if (wave < 4) {
        const float* sp = scr + (wave * 64 + lane) * 20;
#pragma unroll
        for (int u = 0; u < 4; ++u) o[u] += *(const fx4*)(sp + u * 4);
        l += sp[16];
        const float inv = 1.0f / l;
        float* orow = Og + ((size_t)bh * S_LEN + qbase + c) * D_KV + g * 4;
#pragma unroll
        for (int u = 0; u < 4; ++u) {
            fx4 r = o[u] * inv;
            *(fx4*)(orow + u * 16) = r;
        }
    }
}

extern "C" void kernel_launch(void* const* d_in, const int* in_sizes, int n_in,
                              void* d_out, int out_size, void* d_ws, size_t ws_size,
                              hipStream_t stream) {
    const float* Q = (const float*)d_in[0];
    const float* K = (const float*)d_in[1];
    const float* V = (const float*)d_in[2];
    const float* M = (const float*)d_in[3];
    float*       O = (float*)d_out;
    dim3 grid(S_LEN / BQ, 32);   // 32 q-tiles x (B*H)=32
    attn_fwd<<<grid, 512, 0, stream>>>(Q, K, V, M, O);
}

// Round 2
// 198.811 us; speedup vs baseline: 1.4528x; 1.4528x over previous
//
#include <hip/hip_runtime.h>
#include <math.h>

#define S_LEN 2048
#define D_KV  64
#define BQ    128   // q rows per block: 8 waves x 16
#define BK    64
#define NT    (S_LEN / BK)   // 32 k-tiles

typedef __attribute__((ext_vector_type(8))) short bh8;   // 8 bf16 (MFMA A/B frag)
typedef __attribute__((ext_vector_type(4))) float fx4;   // MFMA C/D frag / float4
typedef __attribute__((ext_vector_type(4))) unsigned int u32x4;
typedef __attribute__((ext_vector_type(2))) unsigned int u32x2;

__device__ __forceinline__ unsigned cvt2(float a, float b) {
    unsigned r;
    asm("v_cvt_pk_bf16_f32 %0, %1, %2" : "=v"(r) : "v"(a), "v"(b));
    return r;
}

// XOR-swizzled byte offsets (same function on write and read — both-sides rule)
__device__ __forceinline__ int kswz(int row, int byteoff) {
    return ((row << 7) + byteoff) ^ ((row & 7) << 4);
}
__device__ __forceinline__ int vswz(int d, int colb) {
    return ((d << 7) + colb) ^ (((d >> 2) & 7) << 4);
}

__global__ __launch_bounds__(512, 4)
void attn_fwd(const float* __restrict__ Qg, const float* __restrict__ Kg,
              const float* __restrict__ Vg, const float* __restrict__ Mg,
              float* __restrict__ Og)
{
    // single-buffer LDS: K [64][64] bf16 swizzled (8KB) + V^T permuted (8KB)
    __shared__ __align__(16) char smem[16384];
    short* kb = (short*)smem;
    short* vb = (short*)(smem + 8192);

    const int tid  = threadIdx.x;
    const int wave = tid >> 6;
    const int lane = tid & 63;
    const int g    = lane >> 4;   // quad 0..3
    const int c    = lane & 15;   // q row within wave tile

    // ---- XCD-aware bijective swizzle: 512 blocks % 8 == 0; 64 contiguous/XCD
    const int flat = blockIdx.x + (int)gridDim.x * blockIdx.y;   // 0..511
    const int nsw  = (flat & 7) * 64 + (flat >> 3);
    const int qt = nsw & 15;      // q tile
    const int bh = nsw >> 4;      // 0..31
    const int b  = bh >> 4;

    const int qbase = qt * BQ + wave * 16;

    const float* Kp = Kg + (size_t)bh * S_LEN * D_KV;
    const float* Vp = Vg + (size_t)bh * S_LEN * D_KV;
    const float* Qp = Qg + ((size_t)bh * S_LEN + qbase) * D_KV;
    const float* mrow = Mg + (size_t)b * S_LEN * S_LEN
                      + (size_t)(qbase + c) * S_LEN + g * 4;

    // ---- Q as B-frag (col = q = c), scale 1/8 folded in ----
    bh8 qf[2];
#pragma unroll
    for (int kc = 0; kc < 2; ++kc) {
        const float* src = Qp + c * D_KV + kc * 32 + g * 8;
        fx4 a0 = *(const fx4*)(src);
        fx4 a1 = *(const fx4*)(src + 4);
        u32x4 q4 = { cvt2(a0[0] * 0.125f, a0[1] * 0.125f),
                     cvt2(a0[2] * 0.125f, a0[3] * 0.125f),
                     cvt2(a1[0] * 0.125f, a1[1] * 0.125f),
                     cvt2(a1[2] * 0.125f, a1[3] * 0.125f) };
        qf[kc] = __builtin_bit_cast(bh8, q4);
    }

    // ---- staging roles: waves 0-3 stage K, waves 4-7 stage V ----
    const bool isK = (tid < 256);
    const int  stid = tid & 255;
    const int  vk0 = (stid >> 4) << 2;          // V: 4x4 transpose block
    const int  vd0 = (stid & 15) << 2;
    // slot-permuted col base (bytes): col(s) = ((s&15)>>2)*16 + (s>>4)*4 + (s&3)
    const int  vcolb = (((vk0 & 15) >> 2) << 5) + ((vk0 >> 4) << 3);

    fx4 kvr[4];   // prefetch registers (T14 async-stage split)

    // issue global loads for tile at kt into kvr
    auto issue_kv = [&](int kt) {
        if (isK) {
#pragma unroll
            for (int i = 0; i < 4; ++i) {
                const int idx = stid + 256 * i;
                kvr[i] = *(const fx4*)(Kp + (size_t)(kt + (idx >> 4)) * D_KV
                                          + ((idx & 15) << 2));
            }
        } else {
            const float* vsrc = Vp + (size_t)(kt + vk0) * D_KV + vd0;
#pragma unroll
            for (int i = 0; i < 4; ++i)
                kvr[i] = *(const fx4*)(vsrc + i * D_KV);
        }
    };
    // convert kvr -> bf16 and write to swizzled LDS
    auto write_kv = [&]() {
        if (isK) {
#pragma unroll
            for (int i = 0; i < 4; ++i) {
                const int idx = stid + 256 * i;
                const int kr  = idx >> 4;
                const int de  = (idx & 15) << 2;           // float elem offset
                u32x2 w = { cvt2(kvr[i][0], kvr[i][1]), cvt2(kvr[i][2], kvr[i][3]) };
                *(u32x2*)((char*)kb + kswz(kr, de << 1)) = w;
            }
        } else {
#pragma unroll
            for (int i = 0; i < 4; ++i) {
                u32x2 w = { cvt2(kvr[0][i], kvr[1][i]), cvt2(kvr[2][i], kvr[3][i]) };
                *(u32x2*)((char*)vb + vswz(vd0 + i, vcolb)) = w;
            }
        }
    };

    fx4 o[4];                 // O[q=c][d = u*16 + g*4 + r]
#pragma unroll
    for (int u = 0; u < 4; ++u) { fx4 z = {0.f, 0.f, 0.f, 0.f}; o[u] = z; }
    float l = 0.f;

    issue_kv(0);   // prologue prefetch

#pragma unroll 1
    for (int t = 0; t < NT; ++t) {
        const int kt = t * BK;

        // ---- mask loads (newest in flight; staged write below waits only kvr)
        fx4 mv[4];
#pragma unroll
        for (int tt = 0; tt < 4; ++tt)
            mv[tt] = *(const fx4*)(mrow + kt + tt * 16);

        // ---- drain kvr -> LDS, then expose tile to all waves
        write_kv();
        __syncthreads();

        // ---- prefetch next tile while computing this one
        if (t + 1 < NT) issue_kv(kt + BK);

        // ---- QK^T swapped: st[tt] lane(c,g) reg r = S[q=c][key = tt*16+g*4+r]
        fx4 st[4];
#pragma unroll
        for (int tt = 0; tt < 4; ++tt) { fx4 z = {0.f, 0.f, 0.f, 0.f}; st[tt] = z; }
        __builtin_amdgcn_s_setprio(1);
#pragma unroll
        for (int kc = 0; kc < 2; ++kc) {
#pragma unroll
            for (int tt = 0; tt < 4; ++tt) {
                bh8 kf = *(const bh8*)((char*)kb + kswz(tt * 16 + c, (kc << 6) + (g << 4)));
                st[tt] = __builtin_amdgcn_mfma_f32_16x16x32_bf16(kf, qf[kc], st[tt], 0, 0, 0);
            }
        }
        __builtin_amdgcn_s_setprio(0);

        // ---- mask * keep-positive * exp (fixed max 0), pack bf16 in-register
        unsigned pk[8];
#pragma unroll
        for (int tt = 0; tt < 4; ++tt) {
            float tm0 = st[tt][0] * mv[tt][0];
            float tm1 = st[tt][1] * mv[tt][1];
            float tm2 = st[tt][2] * mv[tt][2];
            float tm3 = st[tt][3] * mv[tt][3];
            float p0 = tm0 > 0.f ? __expf(tm0) : 0.f;
            float p1 = tm1 > 0.f ? __expf(tm1) : 0.f;
            float p2 = tm2 > 0.f ? __expf(tm2) : 0.f;
            float p3 = tm3 > 0.f ? __expf(tm3) : 0.f;
            l += (p0 + p1) + (p2 + p3);
            pk[tt * 2 + 0] = cvt2(p0, p1);
            pk[tt * 2 + 1] = cvt2(p2, p3);
        }

        // ---- PV: o[u] += V^T_frag(A) x P(B); P fed straight from registers
        __builtin_amdgcn_s_setprio(1);
#pragma unroll
        for (int tp = 0; tp < 2; ++tp) {
            u32x4 pq = { pk[tp * 4 + 0], pk[tp * 4 + 1],
                         pk[tp * 4 + 2], pk[tp * 4 + 3] };
            bh8 pp = __builtin_bit_cast(bh8, pq);
#pragma unroll
            for (int u = 0; u < 4; ++u) {
                bh8 vv = *(const bh8*)((char*)vb + vswz(u * 16 + c, (g << 5) + (tp << 4)));
                o[u] = __builtin_amdgcn_mfma_f32_16x16x32_bf16(vv, pp, o[u], 0, 0, 0);
            }
        }
        __builtin_amdgcn_s_setprio(0);

        __syncthreads();   // readers done before next tile's LDS writes
    }

    // ---- reduce l across the 4 g-groups sharing row q=c ----
    l += __shfl_xor(l, 16);
    l += __shfl_xor(l, 32);
    const float inv = 1.0f / l;

    // ---- epilogue: O / l, 16B stores; wave covers full 256B rows ----
    float* orow = Og + ((size_t)bh * S_LEN + qbase + c) * D_KV + g * 4;
#pragma unroll
    for (int u = 0; u < 4; ++u) {
        fx4 r = o[u] * inv;
        *(fx4*)(orow + u * 16) = r;
    }
}

extern "C" void kernel_launch(void* const* d_in, const int* in_sizes, int n_in,
                              void* d_out, int out_size, void* d_ws, size_t ws_size,
                              hipStream_t stream) {
    const float* Q = (const float*)d_in[0];
    const float* K = (const float*)d_in[1];
    const float* V = (const float*)d_in[2];
    const float* M = (const float*)d_in[3];
    float*       O = (float*)d_out;
    dim3 grid(S_LEN / BQ, 32);   // 16 q-tiles x (B*H)=32
    attn_fwd<<<grid, 512, 0, stream>>>(Q, K, V, M, O);
}